// Round 4
// baseline (681.499 us; speedup 1.0000x reference)
//
#include <hip/hip_runtime.h>
#include <cstdint>
#include <cstddef>
#include <cmath>

#define SEQ 4096
#define DM  2048

typedef unsigned int u32;
typedef unsigned short u16;
typedef __attribute__((ext_vector_type(8))) short bf16x8;
typedef __attribute__((ext_vector_type(4))) float f32x4;

// ---------------- bf16 helpers (RNE) ----------------
__device__ __forceinline__ u16 f2bf(float f) {
  u32 u = __float_as_uint(f);
  return (u16)((u + 0x7FFFu + ((u >> 16) & 1u)) >> 16);
}
__device__ __forceinline__ float bf2f(u16 h) { return __uint_as_float(((u32)h) << 16); }

// ---------------- threefry dropout (verified round 1, variant 0) ----------------
__device__ __forceinline__ u32 rotl32(u32 x, int r) { return (x << r) | (x >> (32 - r)); }

__device__ __forceinline__ void tf2x32(u32 c0, u32 c1, u32& o0, u32& o1) {
  const u32 k0 = 0u, k1 = 42u, k2 = 0x1BD11BDAu ^ 0u ^ 42u;
  u32 x0 = c0 + k0;
  u32 x1 = c1 + k1;
#define TFR(r) { x0 += x1; x1 = rotl32(x1, (r)); x1 ^= x0; }
  TFR(13) TFR(15) TFR(26) TFR(6)   x0 += k1; x1 += k2 + 1u;
  TFR(17) TFR(29) TFR(16) TFR(24)  x0 += k2; x1 += k0 + 2u;
  TFR(13) TFR(15) TFR(26) TFR(6)   x0 += k0; x1 += k1 + 3u;
  TFR(17) TFR(29) TFR(16) TFR(24)  x0 += k1; x1 += k2 + 4u;
  TFR(13) TFR(15) TFR(26) TFR(6)   x0 += k2; x1 += k0 + 5u;
#undef TFR
  o0 = x0; o1 = x1;
}

__device__ __forceinline__ bool dropout_keep(u32 idx) {
  u32 a, b; tf2x32(0u, idx, a, b);
  return (((a ^ b) & 0x80000000u) == 0u);
}

// ---------------- async global -> LDS, 16 B/lane ----------------
__device__ __forceinline__ void g2l16(const void* g, void* l) {
  __builtin_amdgcn_global_load_lds((const __attribute__((address_space(1))) u32*)g,
                                   (__attribute__((address_space(3))) u32*)l, 16, 0, 0);
}

#define MFMA16(a, b, c) __builtin_amdgcn_mfma_f32_16x16x32_bf16(a, b, c, 0, 0, 0)

// Fragment-tiled (FT) layout for an operand [R rows][K k]:
// tile = 16 rows x 32 k; elem (rt, kt, lane, j) at (((rt*(K/32)+kt)*64+lane)*8+j),
// where lane holds row rt*16+(lane&15), k kt*32+(lane>>4)*8+j — exactly the
// 16x16x32 MFMA A/B fragment. A wave loads its fragment with ONE dwordx4.

// ---------------------------------------------------------------------------
// SPLIT MFMA GEMM core: C[128x128] = A * B^T, fp32 emulated via hi/lo bf16.
// hi planes: row-major, staged via swizzled global_load_lds (proven R3 path).
// lo planes: FT layout, loaded global->VGPR directly (no LDS, no barrier dep).
// smem: >= 128*64 u16 (16 KB staging); caller may reuse it after return.
// ---------------------------------------------------------------------------
__device__ __forceinline__ void gemm_core_split(
    const u16* __restrict__ Ah, const u16* __restrict__ AlFT,
    const u16* __restrict__ Bh, const u16* __restrict__ BlFT,
    int lda, int ldb, int rowBlock, int colBlock, int kmax,
    f32x4 (&acc)[4][4], u16* smem)
{
  u16* Als = smem;            // 128*32
  u16* Bls = smem + 4096;     // 128*32
  const int tid  = threadIdx.x;
  const int wid  = tid >> 6;
  const int lane = tid & 63;
  const int wr   = (wid & 1) << 6;
  const int wc   = (wid >> 1) << 6;
  const int lrow = lane & 15;
  const int lk   = (((lane >> 4) ^ ((lrow >> 1) & 3)) << 3);
  const int srow = wid * 32 + (lane >> 2);
  const int skol = (((lane & 3) ^ ((lane >> 3) & 3)) << 3);
  const int KA32 = lda >> 5, KB32 = ldb >> 5;
  const int rtA = (rowBlock >> 4) + ((wid & 1) << 2);   // wave's first A row-tile
  const int rtB = (colBlock >> 4) + ((wid >> 1) << 2);  // wave's first B row-tile

  const f32x4 zero = {0.f, 0.f, 0.f, 0.f};
#pragma unroll
  for (int i = 0; i < 4; ++i)
#pragma unroll
    for (int j = 0; j < 4; ++j) acc[i][j] = zero;

  for (int kb = 0; kb < kmax; kb += 32) {
    const int kt = kb >> 5;
    // lo fragments: direct global->VGPR, FT layout (no LDS)
    bf16x8 al[4], bl[4];
#pragma unroll
    for (int r = 0; r < 4; ++r) {
      al[r] = *(const bf16x8*)(AlFT + (((size_t)(rtA + r) * KA32 + kt) * 64 + lane) * 8);
      bl[r] = *(const bf16x8*)(BlFT + (((size_t)(rtB + r) * KB32 + kt) * 64 + lane) * 8);
    }
    // hi staging (swizzled, async)
#pragma unroll
    for (int t = 0; t < 2; ++t) {
      const size_t ga = (size_t)(rowBlock + srow + t * 16) * lda + kb + skol;
      const size_t gb = (size_t)(colBlock + srow + t * 16) * ldb + kb + skol;
      const int lo = (wid * 32 + t * 16) * 32;
      g2l16(Ah + ga, &Als[lo]);
      g2l16(Bh + gb, &Bls[lo]);
    }
    __syncthreads();

    bf16x8 ah[4], bh[4];
#pragma unroll
    for (int r = 0; r < 4; ++r) {
      ah[r] = *(const bf16x8*)&Als[(wr + r * 16 + lrow) * 32 + lk];
      bh[r] = *(const bf16x8*)&Bls[(wc + r * 16 + lrow) * 32 + lk];
    }
#pragma unroll
    for (int r = 0; r < 4; ++r)
#pragma unroll
      for (int c = 0; c < 4; ++c) {
        acc[r][c] = MFMA16(ah[r], bh[c], acc[r][c]);
        acc[r][c] = MFMA16(ah[r], bl[c], acc[r][c]);
        acc[r][c] = MFMA16(al[r], bh[c], acc[r][c]);
      }
    __syncthreads();
  }
}

// Plain bf16 GEMM core (R3 version, hi-only): C[128x128] = A * B^T.
__device__ __forceinline__ void gemm_core(
    const u16* __restrict__ Ah, const u16* __restrict__ Bh,
    int lda, int ldb, int rowBlock, int colBlock, int kmax,
    f32x4 (&acc)[4][4])
{
  __shared__ __align__(16) u16 Als[128 * 32];
  __shared__ __align__(16) u16 Bls[128 * 32];
  const int tid  = threadIdx.x;
  const int wid  = tid >> 6;
  const int lane = tid & 63;
  const int wr   = (wid & 1) << 6;
  const int wc   = (wid >> 1) << 6;
  const int lrow = lane & 15;
  const int lk   = (((lane >> 4) ^ ((lrow >> 1) & 3)) << 3);
  const int srow = wid * 32 + (lane >> 2);
  const int skol = (((lane & 3) ^ ((lane >> 3) & 3)) << 3);

  const f32x4 zero = {0.f, 0.f, 0.f, 0.f};
#pragma unroll
  for (int i = 0; i < 4; ++i)
#pragma unroll
    for (int j = 0; j < 4; ++j) acc[i][j] = zero;

  for (int kb = 0; kb < kmax; kb += 32) {
#pragma unroll
    for (int t = 0; t < 2; ++t) {
      const size_t ga = (size_t)(rowBlock + srow + t * 16) * lda + kb + skol;
      const size_t gb = (size_t)(colBlock + srow + t * 16) * ldb + kb + skol;
      const int lo = (wid * 32 + t * 16) * 32;
      g2l16(Ah + ga, &Als[lo]);
      g2l16(Bh + gb, &Bls[lo]);
    }
    __syncthreads();

    bf16x8 ah[4], bh[4];
#pragma unroll
    for (int r = 0; r < 4; ++r) {
      ah[r] = *(const bf16x8*)&Als[(wr + r * 16 + lrow) * 32 + lk];
      bh[r] = *(const bf16x8*)&Bls[(wc + r * 16 + lrow) * 32 + lk];
    }
#pragma unroll
    for (int r = 0; r < 4; ++r)
#pragma unroll
      for (int c = 0; c < 4; ++c)
        acc[r][c] = MFMA16(ah[r], bh[c], acc[r][c]);
    __syncthreads();
  }
}

// ---------------- split/transpose preprocessing ----------------
// X [4096][2048] fp32 -> Xh row-major bf16 + Xl FT bf16.
__global__ __launch_bounds__(256) void k_split_x(const float* __restrict__ X,
                                                 u16* __restrict__ Xh, u16* __restrict__ Xl) {
  const int wid = threadIdx.x >> 6, lane = threadIdx.x & 63;
  const int kt = blockIdx.x;                 // 0..63
  const int rt = blockIdx.y * 4 + wid;       // 0..255
  const int row = rt * 16 + (lane & 15);
  const int col = kt * 32 + ((lane >> 4) << 3);
  const float* src = X + (size_t)row * DM + col;
  const float4 v0 = *(const float4*)src;
  const float4 v1 = *(const float4*)(src + 4);
  float v[8] = {v0.x, v0.y, v0.z, v0.w, v1.x, v1.y, v1.z, v1.w};
  u16 h[8], l[8];
#pragma unroll
  for (int j = 0; j < 8; ++j) {
    h[j] = f2bf(v[j]);
    l[j] = f2bf(v[j] - bf2f(h[j]));
  }
  u16* hp = Xh + (size_t)row * DM + col;
  *(ushort4*)hp = *(ushort4*)&h[0];
  *(ushort4*)(hp + 4) = *(ushort4*)&h[4];
  u16* lp = Xl + (((size_t)rt * 64 + kt) * 64 + lane) * 8;
  *(ushort4*)lp = *(ushort4*)&l[0];
  *(ushort4*)(lp + 4) = *(ushort4*)&l[4];
}

// W [K=2048][N=2048] fp32 -> transposed Wt[n][k]: hi row-major + lo FT (z<2).
__global__ __launch_bounds__(256) void k_split_w(
    const float* __restrict__ Wq, const float* __restrict__ Wk, const float* __restrict__ Wv,
    u16* __restrict__ Wqh, u16* __restrict__ Wql,
    u16* __restrict__ Wkh, u16* __restrict__ Wkl, u16* __restrict__ Wvh) {
  const int z = blockIdx.z;
  const float* W = (z == 0) ? Wq : (z == 1) ? Wk : Wv;
  u16* Oh = (z == 0) ? Wqh : (z == 1) ? Wkh : Wvh;
  u16* Ol = (z == 0) ? Wql : Wkl;
  __shared__ float t[64][65];
  const int tid = threadIdx.x;
  const int n0 = blockIdx.x * 64, k0 = blockIdx.y * 64;
  const int tx = tid & 63, ty = tid >> 6;
#pragma unroll
  for (int i = 0; i < 16; ++i)
    t[ty * 16 + i][tx] = W[(size_t)(k0 + ty * 16 + i) * DM + n0 + tx];
  __syncthreads();
  // hi: row-major [n][k], each thread 1 n-row x 16 k
  {
    const int nl = tid >> 2, kc = (tid & 3) * 16;
    u16 h[16];
#pragma unroll
    for (int i = 0; i < 16; ++i) h[i] = f2bf(t[kc + i][nl]);
    u16* hp = Oh + (size_t)(n0 + nl) * DM + k0 + kc;
#pragma unroll
    for (int i = 0; i < 4; ++i) *(ushort4*)(hp + i * 4) = *(ushort4*)&h[i * 4];
  }
  // lo: FT over [n][k] (K32 = 64), 8 tiles per block, 2 per wave
  if (z < 2) {
    const int wid = tid >> 6, lane = tid & 63;
#pragma unroll
    for (int kt = 0; kt < 2; ++kt) {
      const int nl = wid * 16 + (lane & 15);
      const int kc = kt * 32 + ((lane >> 4) << 3);
      u16 l[8];
#pragma unroll
      for (int j = 0; j < 8; ++j) {
        const float v = t[kc + j][nl];
        l[j] = f2bf(v - bf2f(f2bf(v)));
      }
      const int rtg = (n0 >> 4) + wid, ktg = (k0 >> 5) + kt;
      u16* lp = Ol + (((size_t)rtg * 64 + ktg) * 64 + lane) * 8;
      *(ushort4*)lp = *(ushort4*)&l[0];
      *(ushort4*)(lp + 4) = *(ushort4*)&l[4];
    }
  }
}

// ---------------- GEMM kernels ----------------
// Q/K projections (bf16x3): out hi row-major + lo FT (for k_scores direct loads).
__global__ __launch_bounds__(256) void k_proj_qk(
    const u16* __restrict__ Xh, const u16* __restrict__ Xl,
    const u16* __restrict__ Wqh, const u16* __restrict__ Wql,
    const u16* __restrict__ Wkh, const u16* __restrict__ Wkl,
    u16* __restrict__ Qh, u16* __restrict__ Ql,
    u16* __restrict__ Kh, u16* __restrict__ Kl, float rscaleQ)
{
  __shared__ __align__(16) u16 smem[128 * 128];   // 16 KB staging, reused by epilogue
  const int z = blockIdx.z;
  const u16* Bh = z ? Wkh : Wqh;
  const u16* Bl = z ? Wkl : Wql;
  u16* Oh = z ? Kh : Qh;
  u16* Ol = z ? Kl : Ql;
  const float rs = z ? 1.0f : rscaleQ;
  const int rowBlock = blockIdx.y * 128, colBlock = blockIdx.x * 128;
  f32x4 acc[4][4];
  gemm_core_split(Xh, Xl, Bh, Bl, DM, DM, rowBlock, colBlock, DM, acc, smem);

  const int lane = threadIdx.x & 63, wid = threadIdx.x >> 6;
  const int lr0 = ((wid & 1) << 6) + ((lane >> 4) << 2);
  const int lc0 = ((wid >> 1) << 6) + (lane & 15);
  // hi -> global (row-major), lo -> LDS transpose buffer
#pragma unroll
  for (int r = 0; r < 4; ++r)
#pragma unroll
    for (int c = 0; c < 4; ++c)
#pragma unroll
      for (int e = 0; e < 4; ++e) {
        const float v = acc[r][c][e] * rs;
        const u16 h = f2bf(v);
        const int lrow = lr0 + r * 16 + e, lcol = lc0 + c * 16;
        Oh[(size_t)(rowBlock + lrow) * DM + colBlock + lcol] = h;
        smem[lrow * 128 + lcol] = f2bf(v - bf2f(h));
      }
  __syncthreads();
  // lo: fragment-order read from LDS, FT-coalesced store (8 tiles/wave)
#pragma unroll
  for (int t8 = 0; t8 < 8; ++t8) {
    const int idx = wid * 8 + t8;
    const int rt = idx >> 2, kt = idx & 3;
    u16 l[8];
#pragma unroll
    for (int j = 0; j < 8; ++j)
      l[j] = smem[(rt * 16 + (lane & 15)) * 128 + kt * 32 + ((lane >> 4) << 3) + j];
    const int rtg = (rowBlock >> 4) + rt, ktg = (colBlock >> 5) + kt;
    u16* lp = Ol + (((size_t)rtg * (DM / 32) + ktg) * 64 + lane) * 8;
    *(ushort4*)lp = *(ushort4*)&l[0];
    *(ushort4*)(lp + 4) = *(ushort4*)&l[4];
  }
}

// V projection (plain bf16), stores transposed Vt[d][s] bf16.
__global__ __launch_bounds__(256) void k_proj_v(
    const u16* __restrict__ Xh, const u16* __restrict__ Wvh, u16* __restrict__ Vt)
{
  f32x4 acc[4][4];
  gemm_core(Xh, Wvh, DM, DM, blockIdx.y * 128, blockIdx.x * 128, DM, acc);

  const int lane = threadIdx.x & 63, wid = threadIdx.x >> 6;
  const int r0 = blockIdx.y * 128 + ((wid & 1) << 6) + ((lane >> 4) << 2);
  const int c0 = blockIdx.x * 128 + ((wid >> 1) << 6) + (lane & 15);
#pragma unroll
  for (int r = 0; r < 4; ++r)
#pragma unroll
    for (int c = 0; c < 4; ++c) {
      const int d = c0 + c * 16;
      const int s0 = r0 + r * 16;
      ushort4 pk;
      pk.x = f2bf(acc[r][c][0]); pk.y = f2bf(acc[r][c][1]);
      pk.z = f2bf(acc[r][c][2]); pk.w = f2bf(acc[r][c][3]);
      *(ushort4*)(Vt + (size_t)d * SEQ + s0) = pk;
    }
}

// S = (Q/scale) @ K^T (bf16x3), 528 lower-triangular blocks, fp32 out.
__global__ __launch_bounds__(256) void k_scores(
    const u16* __restrict__ Qh, const u16* __restrict__ Ql,
    const u16* __restrict__ Kh, const u16* __restrict__ Kl, float* __restrict__ S)
{
  __shared__ __align__(16) u16 smem[128 * 64];
  const int bid = blockIdx.x;
  int by = (int)((sqrtf(8.0f * (float)bid + 1.0f) - 1.0f) * 0.5f);
  while ((by + 1) * (by + 2) / 2 <= bid) ++by;
  while (by * (by + 1) / 2 > bid) --by;
  const int bx = bid - by * (by + 1) / 2;

  f32x4 acc[4][4];
  gemm_core_split(Qh, Ql, Kh, Kl, DM, DM, by * 128, bx * 128, DM, acc, smem);

  const int lane = threadIdx.x & 63, wid = threadIdx.x >> 6;
  const int r0 = by * 128 + ((wid & 1) << 6) + ((lane >> 4) << 2);
  const int c0 = bx * 128 + ((wid >> 1) << 6) + (lane & 15);
#pragma unroll
  for (int r = 0; r < 4; ++r)
#pragma unroll
    for (int c = 0; c < 4; ++c)
#pragma unroll
      for (int e = 0; e < 4; ++e)
        S[(size_t)(r0 + r * 16 + e) * SEQ + (c0 + c * 16)] = acc[r][c][e];
}

// Row softmax (causal) + inverted dropout; S fp32 -> P bf16 (zero-padded to 128).
__global__ __launch_bounds__(256) void k_softmax_dropout(const float* __restrict__ S,
                                                         u16* __restrict__ P) {
  const int row = blockIdx.x;
  const int n = row + 1;
  const int nt = (n + 1023) >> 10;
  const int tid = threadIdx.x;
  __shared__ float buf[SEQ];
  __shared__ float red[4];
  __shared__ float bcast;
  const float* srow = S + (size_t)row * SEQ;

  float lmax = -INFINITY;
  for (int t = 0; t < nt; ++t) {
    int j4 = tid + t * 256;
    float4 v = *(const float4*)(srow + (size_t)j4 * 4);
    int b = j4 * 4;
    float x0 = (b + 0 < n) ? v.x : -INFINITY;
    float x1 = (b + 1 < n) ? v.y : -INFINITY;
    float x2 = (b + 2 < n) ? v.z : -INFINITY;
    float x3 = (b + 3 < n) ? v.w : -INFINITY;
    buf[b + 0] = x0; buf[b + 1] = x1; buf[b + 2] = x2; buf[b + 3] = x3;
    lmax = fmaxf(lmax, fmaxf(fmaxf(x0, x1), fmaxf(x2, x3)));
  }
  for (int off = 32; off > 0; off >>= 1) lmax = fmaxf(lmax, __shfl_down(lmax, off, 64));
  if ((tid & 63) == 0) red[tid >> 6] = lmax;
  __syncthreads();
  if (tid == 0) bcast = fmaxf(fmaxf(red[0], red[1]), fmaxf(red[2], red[3]));
  __syncthreads();
  const float m = bcast;

  float lsum = 0.f;
  for (int t = 0; t < nt; ++t) {
    int b = (tid + t * 256) * 4;
    float e0 = expf(buf[b + 0] - m);
    float e1 = expf(buf[b + 1] - m);
    float e2 = expf(buf[b + 2] - m);
    float e3 = expf(buf[b + 3] - m);
    buf[b + 0] = e0; buf[b + 1] = e1; buf[b + 2] = e2; buf[b + 3] = e3;
    lsum += (e0 + e1) + (e2 + e3);
  }
  for (int off = 32; off > 0; off >>= 1) lsum += __shfl_down(lsum, off, 64);
  if ((tid & 63) == 0) red[tid >> 6] = lsum;
  __syncthreads();
  if (tid == 0) bcast = (red[0] + red[1]) + (red[2] + red[3]);
  __syncthreads();
  const float total = bcast;

  u16* prow = P + (size_t)row * SEQ;
  const int zeroEnd = ((row >> 7) + 1) << 7;
  for (int j = tid; j < zeroEnd; j += 256) {
    float out = 0.f;
    if (j < n) {
      const float w = buf[j] / total;
      out = dropout_keep((u32)(row * SEQ + j)) ? w * 2.0f : 0.f;
    }
    prow[j] = f2bf(out);
  }
}

// context = P @ V (plain bf16, causal-truncated K-loop), fp32 out; heavy rows first.
__global__ __launch_bounds__(256) void k_pv(const u16* __restrict__ P,
                                            const u16* __restrict__ Vt,
                                            float* __restrict__ O) {
  const int by = (SEQ / 128 - 1) - blockIdx.y;
  f32x4 acc[4][4];
  gemm_core(P, Vt, SEQ, SEQ, by * 128, blockIdx.x * 128, (by + 1) * 128, acc);

  const int lane = threadIdx.x & 63, wid = threadIdx.x >> 6;
  const int r0 = by * 128 + ((wid & 1) << 6) + ((lane >> 4) << 2);
  const int c0 = blockIdx.x * 128 + ((wid >> 1) << 6) + (lane & 15);
#pragma unroll
  for (int r = 0; r < 4; ++r)
#pragma unroll
    for (int c = 0; c < 4; ++c)
#pragma unroll
      for (int e = 0; e < 4; ++e)
        O[(size_t)(r0 + r * 16 + e) * DM + (c0 + c * 16)] = acc[r][c][e];
}

extern "C" void kernel_launch(void* const* d_in, const int* in_sizes, int n_in,
                              void* d_out, int out_size, void* d_ws, size_t ws_size,
                              hipStream_t stream) {
  const float* x  = (const float*)d_in[0];
  const float* Wq = (const float*)d_in[1];
  const float* Wk = (const float*)d_in[2];
  const float* Wv = (const float*)d_in[3];

  // workspace layout (u16 elements; 152 MiB total)
  const size_t PL = (size_t)SEQ * DM;   // 16 MiB/plane
  const size_t WL = (size_t)DM * DM;    // 8 MiB/plane
  u16* base = (u16*)d_ws;
  u16* Qh = base;                // [SEQ][DM] row-major
  u16* Ql = Qh + PL;             // FT
  u16* Kh = Ql + PL;             // row-major
  u16* Kl = Kh + PL;             // FT
  u16* Vt = Kl + PL;             // [DM][SEQ]
  u16* P  = base;                // [SEQ][SEQ] bf16, overlays Qh+Ql (dead by then)
  u16* regA = Vt + PL;           // offset 80 MiB
  u16* Xh  = regA;               // [SEQ][DM] row-major
  u16* Xl  = Xh + PL;            // FT
  u16* Wqh = Xl + PL;            // [DM][DM] transposed row-major
  u16* Wql = Wqh + WL;           // FT
  u16* Wkh = Wql + WL;
  u16* Wkl = Wkh + WL;
  u16* Wvh = Wkl + WL;
  float* S = (float*)regA;       // [SEQ][SEQ] fp32, overlays X/W splits (dead by then)

  const float rscale = 1.0f / sqrtf(2048.0f);
  dim3 blk(256);
  k_split_x<<<dim3(DM / 32, SEQ / 64), blk, 0, stream>>>(x, Xh, Xl);
  k_split_w<<<dim3(DM / 64, DM / 64, 3), blk, 0, stream>>>(Wq, Wk, Wv, Wqh, Wql, Wkh, Wkl, Wvh);
  k_proj_qk<<<dim3(DM / 128, SEQ / 128, 2), blk, 0, stream>>>(Xh, Xl, Wqh, Wql, Wkh, Wkl,
                                                              Qh, Ql, Kh, Kl, rscale);
  k_proj_v<<<dim3(DM / 128, SEQ / 128), blk, 0, stream>>>(Xh, Wvh, Vt);
  k_scores<<<dim3((SEQ / 128) * (SEQ / 128 + 1) / 2), blk, 0, stream>>>(Qh, Ql, Kh, Kl, S);
  k_softmax_dropout<<<dim3(SEQ), blk, 0, stream>>>(S, P);
  k_pv<<<dim3(DM / 128, SEQ / 128), blk, 0, stream>>>(P, Vt, (float*)d_out);
}

// Round 6
// 665.240 us; speedup vs baseline: 1.0244x; 1.0244x over previous
//
#include <hip/hip_runtime.h>
#include <cstdint>
#include <cstddef>
#include <cmath>

#define SEQ 4096
#define DM  2048
#define NSC ((SEQ / 128) * (SEQ / 128 + 1) / 2)   // 528 scores tiles

typedef unsigned int u32;
typedef unsigned short u16;
typedef __attribute__((ext_vector_type(8))) short bf16x8;
typedef __attribute__((ext_vector_type(4))) float f32x4;

// ---------------- bf16 helpers (RNE) ----------------
__device__ __forceinline__ u16 f2bf(float f) {
  u32 u = __float_as_uint(f);
  return (u16)((u + 0x7FFFu + ((u >> 16) & 1u)) >> 16);
}
__device__ __forceinline__ float bf2f(u16 h) { return __uint_as_float(((u32)h) << 16); }

// ---------------- threefry dropout (verified round 1, variant 0) ----------------
__device__ __forceinline__ u32 rotl32(u32 x, int r) { return (x << r) | (x >> (32 - r)); }

__device__ __forceinline__ void tf2x32(u32 c0, u32 c1, u32& o0, u32& o1) {
  const u32 k0 = 0u, k1 = 42u, k2 = 0x1BD11BDAu ^ 0u ^ 42u;
  u32 x0 = c0 + k0;
  u32 x1 = c1 + k1;
#define TFR(r) { x0 += x1; x1 = rotl32(x1, (r)); x1 ^= x0; }
  TFR(13) TFR(15) TFR(26) TFR(6)   x0 += k1; x1 += k2 + 1u;
  TFR(17) TFR(29) TFR(16) TFR(24)  x0 += k2; x1 += k0 + 2u;
  TFR(13) TFR(15) TFR(26) TFR(6)   x0 += k0; x1 += k1 + 3u;
  TFR(17) TFR(29) TFR(16) TFR(24)  x0 += k1; x1 += k2 + 4u;
  TFR(13) TFR(15) TFR(26) TFR(6)   x0 += k2; x1 += k0 + 5u;
#undef TFR
  o0 = x0; o1 = x1;
}

__device__ __forceinline__ bool dropout_keep(u32 idx) {
  u32 a, b; tf2x32(0u, idx, a, b);
  return (((a ^ b) & 0x80000000u) == 0u);
}

// ---------------- async global -> LDS, 16 B/lane ----------------
__device__ __forceinline__ void g2l16(const void* g, void* l) {
  __builtin_amdgcn_global_load_lds((const __attribute__((address_space(1))) u32*)g,
                                   (__attribute__((address_space(3))) u32*)l, 16, 0, 0);
}

#define MFMA16(a, b, c) __builtin_amdgcn_mfma_f32_16x16x32_bf16(a, b, c, 0, 0, 0)

// Fragment-tiled (FT) layout for an operand [R rows][K k]:
// tile = 16 rows x 32 k; elem (rt, kt, lane, j) at (((rt*(K/32)+kt)*64+lane)*8+j).

// ---------------------------------------------------------------------------
// SPLIT MFMA GEMM core, BK=64: C[128x128] = A*B^T (fp32 emulated via hi/lo).
// hi: row-major via swizzled global_load_lds; lo: FT direct global->VGPR.
// smem: 16384 u16 (32 KB): Als[2][4096] | Bls[2][4096].
// ---------------------------------------------------------------------------
__device__ __forceinline__ void gemm_core_split(
    const u16* __restrict__ Ah, const u16* __restrict__ AlFT,
    const u16* __restrict__ Bh, const u16* __restrict__ BlFT,
    int lda, int ldb, int rowBlock, int colBlock, int kmax,
    f32x4 (&acc)[4][4], u16* smem)
{
  u16* Als = smem;
  u16* Bls = smem + 8192;
  const int tid  = threadIdx.x;
  const int wid  = tid >> 6;
  const int lane = tid & 63;
  const int wr   = (wid & 1) << 6;
  const int wc   = (wid >> 1) << 6;
  const int lrow = lane & 15;
  const int lk   = (((lane >> 4) ^ ((lrow >> 1) & 3)) << 3);
  const int srow = wid * 32 + (lane >> 2);
  const int skol = (((lane & 3) ^ ((lane >> 3) & 3)) << 3);
  const int KA32 = lda >> 5, KB32 = ldb >> 5;
  const int rtA = (rowBlock >> 4) + ((wid & 1) << 2);
  const int rtB = (colBlock >> 4) + ((wid >> 1) << 2);

  const f32x4 zero = {0.f, 0.f, 0.f, 0.f};
#pragma unroll
  for (int i = 0; i < 4; ++i)
#pragma unroll
    for (int j = 0; j < 4; ++j) acc[i][j] = zero;

  for (int kb = 0; kb < kmax; kb += 64) {
#pragma unroll
    for (int h = 0; h < 2; ++h)
#pragma unroll
      for (int t = 0; t < 2; ++t) {
        const size_t ga = (size_t)(rowBlock + srow + t * 16) * lda + kb + h * 32 + skol;
        const size_t gb = (size_t)(colBlock + srow + t * 16) * ldb + kb + h * 32 + skol;
        const int lo = h * 4096 + (wid * 32 + t * 16) * 32;
        g2l16(Ah + ga, &Als[lo]);
        g2l16(Bh + gb, &Bls[lo]);
      }
    __syncthreads();

#pragma unroll
    for (int h = 0; h < 2; ++h) {
      const int kt = (kb >> 5) + h;
      bf16x8 al[4], bl[4], ah[4], bh[4];
#pragma unroll
      for (int r = 0; r < 4; ++r) {
        al[r] = *(const bf16x8*)(AlFT + (((size_t)(rtA + r) * KA32 + kt) * 64 + lane) * 8);
        bl[r] = *(const bf16x8*)(BlFT + (((size_t)(rtB + r) * KB32 + kt) * 64 + lane) * 8);
        ah[r] = *(const bf16x8*)&Als[h * 4096 + (wr + r * 16 + lrow) * 32 + lk];
        bh[r] = *(const bf16x8*)&Bls[h * 4096 + (wc + r * 16 + lrow) * 32 + lk];
      }
#pragma unroll
      for (int r = 0; r < 4; ++r)
#pragma unroll
        for (int c = 0; c < 4; ++c) {
          acc[r][c] = MFMA16(ah[r], bh[c], acc[r][c]);
          acc[r][c] = MFMA16(ah[r], bl[c], acc[r][c]);
          acc[r][c] = MFMA16(al[r], bh[c], acc[r][c]);
        }
    }
    __syncthreads();
  }
}

// Plain bf16 GEMM core, BK=64: C[128x128] = A * B^T. smem: 16384 u16.
__device__ __forceinline__ void gemm_core(
    const u16* __restrict__ Ah, const u16* __restrict__ Bh,
    int lda, int ldb, int rowBlock, int colBlock, int kmax,
    f32x4 (&acc)[4][4], u16* smem)
{
  u16* Als = smem;
  u16* Bls = smem + 8192;
  const int tid  = threadIdx.x;
  const int wid  = tid >> 6;
  const int lane = tid & 63;
  const int wr   = (wid & 1) << 6;
  const int wc   = (wid >> 1) << 6;
  const int lrow = lane & 15;
  const int lk   = (((lane >> 4) ^ ((lrow >> 1) & 3)) << 3);
  const int srow = wid * 32 + (lane >> 2);
  const int skol = (((lane & 3) ^ ((lane >> 3) & 3)) << 3);

  const f32x4 zero = {0.f, 0.f, 0.f, 0.f};
#pragma unroll
  for (int i = 0; i < 4; ++i)
#pragma unroll
    for (int j = 0; j < 4; ++j) acc[i][j] = zero;

  for (int kb = 0; kb < kmax; kb += 64) {
#pragma unroll
    for (int h = 0; h < 2; ++h)
#pragma unroll
      for (int t = 0; t < 2; ++t) {
        const size_t ga = (size_t)(rowBlock + srow + t * 16) * lda + kb + h * 32 + skol;
        const size_t gb = (size_t)(colBlock + srow + t * 16) * ldb + kb + h * 32 + skol;
        const int lo = h * 4096 + (wid * 32 + t * 16) * 32;
        g2l16(Ah + ga, &Als[lo]);
        g2l16(Bh + gb, &Bls[lo]);
      }
    __syncthreads();

#pragma unroll
    for (int h = 0; h < 2; ++h) {
      bf16x8 ah[4], bh[4];
#pragma unroll
      for (int r = 0; r < 4; ++r) {
        ah[r] = *(const bf16x8*)&Als[h * 4096 + (wr + r * 16 + lrow) * 32 + lk];
        bh[r] = *(const bf16x8*)&Bls[h * 4096 + (wc + r * 16 + lrow) * 32 + lk];
      }
#pragma unroll
      for (int r = 0; r < 4; ++r)
#pragma unroll
        for (int c = 0; c < 4; ++c)
          acc[r][c] = MFMA16(ah[r], bh[c], acc[r][c]);
    }
    __syncthreads();
  }
}

// ---------------- fused split/transpose preprocessing ----------------
__global__ __launch_bounds__(256) void k_split_all(
    const float* __restrict__ X, u16* __restrict__ Xh, u16* __restrict__ Xl,
    const float* __restrict__ Wq, const float* __restrict__ Wk, const float* __restrict__ Wv,
    u16* __restrict__ Wqh, u16* __restrict__ Wql,
    u16* __restrict__ Wkh, u16* __restrict__ Wkl, u16* __restrict__ Wvh) {
  __shared__ float t[64][65];
  const int bid = blockIdx.x;
  const int tid = threadIdx.x;
  const int wid = tid >> 6, lane = tid & 63;

  if (bid < 4096) {
    const int kt = bid & 63;
    const int rt = (bid >> 6) * 4 + wid;
    const int row = rt * 16 + (lane & 15);
    const int col = kt * 32 + ((lane >> 4) << 3);
    const float* src = X + (size_t)row * DM + col;
    const float4 v0 = *(const float4*)src;
    const float4 v1 = *(const float4*)(src + 4);
    float v[8] = {v0.x, v0.y, v0.z, v0.w, v1.x, v1.y, v1.z, v1.w};
    u16 h[8], l[8];
#pragma unroll
    for (int j = 0; j < 8; ++j) {
      h[j] = f2bf(v[j]);
      l[j] = f2bf(v[j] - bf2f(h[j]));
    }
    u16* hp = Xh + (size_t)row * DM + col;
    *(ushort4*)hp = *(ushort4*)&h[0];
    *(ushort4*)(hp + 4) = *(ushort4*)&h[4];
    u16* lp = Xl + (((size_t)rt * 64 + kt) * 64 + lane) * 8;
    *(ushort4*)lp = *(ushort4*)&l[0];
    *(ushort4*)(lp + 4) = *(ushort4*)&l[4];
    return;
  }

  const int r = bid - 4096;
  const int z = r >> 10;
  const int rem = r & 1023;
  const int n0 = (rem & 31) * 64, k0 = (rem >> 5) * 64;
  const float* W = (z == 0) ? Wq : (z == 1) ? Wk : Wv;
  u16* Oh = (z == 0) ? Wqh : (z == 1) ? Wkh : Wvh;
  u16* Ol = (z == 0) ? Wql : Wkl;
  const int tx = tid & 63, ty = tid >> 6;
#pragma unroll
  for (int i = 0; i < 16; ++i)
    t[ty * 16 + i][tx] = W[(size_t)(k0 + ty * 16 + i) * DM + n0 + tx];
  __syncthreads();
  {
    const int nl = tid >> 2, kc = (tid & 3) * 16;
    u16 h[16];
#pragma unroll
    for (int i = 0; i < 16; ++i) h[i] = f2bf(t[kc + i][nl]);
    u16* hp = Oh + (size_t)(n0 + nl) * DM + k0 + kc;
#pragma unroll
    for (int i = 0; i < 4; ++i) *(ushort4*)(hp + i * 4) = *(ushort4*)&h[i * 4];
  }
  if (z < 2) {
#pragma unroll
    for (int kt = 0; kt < 2; ++kt) {
      const int nl = wid * 16 + (lane & 15);
      const int kc = kt * 32 + ((lane >> 4) << 3);
      u16 l[8];
#pragma unroll
      for (int j = 0; j < 8; ++j) {
        const float v = t[kc + j][nl];
        l[j] = f2bf(v - bf2f(f2bf(v)));
      }
      const int rtg = (n0 >> 4) + wid, ktg = (k0 >> 5) + kt;
      u16* lp = Ol + (((size_t)rtg * 64 + ktg) * 64 + lane) * 8;
      *(ushort4*)lp = *(ushort4*)&l[0];
      *(ushort4*)(lp + 4) = *(ushort4*)&l[4];
    }
  }
}

// ---------------- fused Q/K/V projections ----------------
// z=0: Q (split, *1/sqrt(d), hi+lo FT out)  z=1: K (same, no scale)
// z=2: V (plain bf16, transposed Vt out) — runs after z=0/1; Xh still live here,
// S is only written later by k_scores (no overlay race, unlike R5's k_sv).
__global__ __launch_bounds__(256) void k_proj_qkv(
    const u16* __restrict__ Xh, const u16* __restrict__ Xl,
    const u16* __restrict__ Wqh, const u16* __restrict__ Wql,
    const u16* __restrict__ Wkh, const u16* __restrict__ Wkl,
    const u16* __restrict__ Wvh,
    u16* __restrict__ Qh, u16* __restrict__ Ql,
    u16* __restrict__ Kh, u16* __restrict__ Kl,
    u16* __restrict__ Vt, float rscaleQ)
{
  __shared__ __align__(16) u16 smem[16384];   // 32 KB staging, reused by epilogue
  const int z = blockIdx.z;
  const int rowBlock = blockIdx.y * 128, colBlock = blockIdx.x * 128;
  const int lane = threadIdx.x & 63, wid = threadIdx.x >> 6;

  if (z == 2) {
    f32x4 acc[4][4];
    gemm_core(Xh, Wvh, DM, DM, rowBlock, colBlock, DM, acc, smem);
    const int r0 = rowBlock + ((wid & 1) << 6) + ((lane >> 4) << 2);
    const int c0 = colBlock + ((wid >> 1) << 6) + (lane & 15);
#pragma unroll
    for (int r = 0; r < 4; ++r)
#pragma unroll
      for (int c = 0; c < 4; ++c) {
        ushort4 pk;
        pk.x = f2bf(acc[r][c][0]); pk.y = f2bf(acc[r][c][1]);
        pk.z = f2bf(acc[r][c][2]); pk.w = f2bf(acc[r][c][3]);
        *(ushort4*)(Vt + (size_t)(c0 + c * 16) * SEQ + r0 + r * 16) = pk;
      }
    return;
  }

  const u16* Bh = z ? Wkh : Wqh;
  const u16* Bl = z ? Wkl : Wql;
  u16* Oh = z ? Kh : Qh;
  u16* Ol = z ? Kl : Ql;
  const float rs = z ? 1.0f : rscaleQ;
  f32x4 acc[4][4];
  gemm_core_split(Xh, Xl, Bh, Bl, DM, DM, rowBlock, colBlock, DM, acc, smem);

  const int lr0 = ((wid & 1) << 6) + ((lane >> 4) << 2);
  const int lc0 = ((wid >> 1) << 6) + (lane & 15);
#pragma unroll
  for (int r = 0; r < 4; ++r)
#pragma unroll
    for (int c = 0; c < 4; ++c)
#pragma unroll
      for (int e = 0; e < 4; ++e) {
        const float v = acc[r][c][e] * rs;
        const u16 h = f2bf(v);
        const int lrow = lr0 + r * 16 + e, lcol = lc0 + c * 16;
        Oh[(size_t)(rowBlock + lrow) * DM + colBlock + lcol] = h;
        smem[lrow * 128 + lcol] = f2bf(v - bf2f(h));
      }
  __syncthreads();
#pragma unroll
  for (int t8 = 0; t8 < 8; ++t8) {
    const int idx = wid * 8 + t8;
    const int rt = idx >> 2, kt = idx & 3;
    u16 l[8];
#pragma unroll
    for (int j = 0; j < 8; ++j)
      l[j] = smem[(rt * 16 + (lane & 15)) * 128 + kt * 32 + ((lane >> 4) << 3) + j];
    const int rtg = (rowBlock >> 4) + rt, ktg = (colBlock >> 5) + kt;
    u16* lp = Ol + (((size_t)rtg * (DM / 32) + ktg) * 64 + lane) * 8;
    *(ushort4*)lp = *(ushort4*)&l[0];
    *(ushort4*)(lp + 4) = *(ushort4*)&l[4];
  }
}

// S = (Q/scale) @ K^T (bf16x3), 528 lower-triangular blocks, fp32 out.
// Safe to overlay S on X/W splits: proj kernels completed before this launch.
__global__ __launch_bounds__(256) void k_scores(
    const u16* __restrict__ Qh, const u16* __restrict__ Ql,
    const u16* __restrict__ Kh, const u16* __restrict__ Kl, float* __restrict__ S)
{
  __shared__ __align__(16) u16 smem[16384];
  const int bid = blockIdx.x;
  int by = (int)((sqrtf(8.0f * (float)bid + 1.0f) - 1.0f) * 0.5f);
  while ((by + 1) * (by + 2) / 2 <= bid) ++by;
  while (by * (by + 1) / 2 > bid) --by;
  const int bx = bid - by * (by + 1) / 2;

  f32x4 acc[4][4];
  gemm_core_split(Qh, Ql, Kh, Kl, DM, DM, by * 128, bx * 128, DM, acc, smem);

  const int lane = threadIdx.x & 63, wid = threadIdx.x >> 6;
  const int r0 = by * 128 + ((wid & 1) << 6) + ((lane >> 4) << 2);
  const int c0 = bx * 128 + ((wid >> 1) << 6) + (lane & 15);
#pragma unroll
  for (int r = 0; r < 4; ++r)
#pragma unroll
    for (int c = 0; c < 4; ++c)
#pragma unroll
      for (int e = 0; e < 4; ++e)
        S[(size_t)(r0 + r * 16 + e) * SEQ + (c0 + c * 16)] = acc[r][c][e];
}

// Row softmax (causal) + inverted dropout; S fp32 -> P bf16 (zero-padded to 128).
__global__ __launch_bounds__(256) void k_softmax_dropout(const float* __restrict__ S,
                                                         u16* __restrict__ P) {
  const int row = blockIdx.x;
  const int n = row + 1;
  const int nt = (n + 1023) >> 10;
  const int tid = threadIdx.x;
  __shared__ float buf[SEQ];
  __shared__ float red[4];
  __shared__ float bcast;
  const float* srow = S + (size_t)row * SEQ;

  float lmax = -INFINITY;
  for (int t = 0; t < nt; ++t) {
    int j4 = tid + t * 256;
    float4 v = *(const float4*)(srow + (size_t)j4 * 4);
    int b = j4 * 4;
    float x0 = (b + 0 < n) ? v.x : -INFINITY;
    float x1 = (b + 1 < n) ? v.y : -INFINITY;
    float x2 = (b + 2 < n) ? v.z : -INFINITY;
    float x3 = (b + 3 < n) ? v.w : -INFINITY;
    buf[b + 0] = x0; buf[b + 1] = x1; buf[b + 2] = x2; buf[b + 3] = x3;
    lmax = fmaxf(lmax, fmaxf(fmaxf(x0, x1), fmaxf(x2, x3)));
  }
  for (int off = 32; off > 0; off >>= 1) lmax = fmaxf(lmax, __shfl_down(lmax, off, 64));
  if ((tid & 63) == 0) red[tid >> 6] = lmax;
  __syncthreads();
  if (tid == 0) bcast = fmaxf(fmaxf(red[0], red[1]), fmaxf(red[2], red[3]));
  __syncthreads();
  const float m = bcast;

  float lsum = 0.f;
  for (int t = 0; t < nt; ++t) {
    int b = (tid + t * 256) * 4;
    float e0 = expf(buf[b + 0] - m);
    float e1 = expf(buf[b + 1] - m);
    float e2 = expf(buf[b + 2] - m);
    float e3 = expf(buf[b + 3] - m);
    buf[b + 0] = e0; buf[b + 1] = e1; buf[b + 2] = e2; buf[b + 3] = e3;
    lsum += (e0 + e1) + (e2 + e3);
  }
  for (int off = 32; off > 0; off >>= 1) lsum += __shfl_down(lsum, off, 64);
  if ((tid & 63) == 0) red[tid >> 6] = lsum;
  __syncthreads();
  if (tid == 0) bcast = (red[0] + red[1]) + (red[2] + red[3]);
  __syncthreads();
  const float total = bcast;

  u16* prow = P + (size_t)row * SEQ;
  const int zeroEnd = ((row >> 7) + 1) << 7;
  for (int j = tid; j < zeroEnd; j += 256) {
    float out = 0.f;
    if (j < n) {
      const float w = buf[j] / total;
      out = dropout_keep((u32)(row * SEQ + j)) ? w * 2.0f : 0.f;
    }
    prow[j] = f2bf(out);
  }
}

// context = P @ V (plain bf16, causal-truncated K-loop), fp32 out; heavy rows first.
__global__ __launch_bounds__(256) void k_pv(const u16* __restrict__ P,
                                            const u16* __restrict__ Vt,
                                            float* __restrict__ O) {
  __shared__ __align__(16) u16 smem[16384];
  const int by = (SEQ / 128 - 1) - blockIdx.y;
  f32x4 acc[4][4];
  gemm_core(P, Vt, SEQ, SEQ, by * 128, blockIdx.x * 128, (by + 1) * 128, acc, smem);

  const int lane = threadIdx.x & 63, wid = threadIdx.x >> 6;
  const int r0 = by * 128 + ((wid & 1) << 6) + ((lane >> 4) << 2);
  const int c0 = blockIdx.x * 128 + ((wid >> 1) << 6) + (lane & 15);
#pragma unroll
  for (int r = 0; r < 4; ++r)
#pragma unroll
    for (int c = 0; c < 4; ++c)
#pragma unroll
      for (int e = 0; e < 4; ++e)
        O[(size_t)(r0 + r * 16 + e) * DM + (c0 + c * 16)] = acc[r][c][e];
}

extern "C" void kernel_launch(void* const* d_in, const int* in_sizes, int n_in,
                              void* d_out, int out_size, void* d_ws, size_t ws_size,
                              hipStream_t stream) {
  const float* x  = (const float*)d_in[0];
  const float* Wq = (const float*)d_in[1];
  const float* Wk = (const float*)d_in[2];
  const float* Wv = (const float*)d_in[3];

  // workspace layout (u16 elements; <=152 MiB)
  const size_t PL = (size_t)SEQ * DM;   // 16 MiB/plane
  const size_t WL = (size_t)DM * DM;    // 8 MiB/plane
  u16* base = (u16*)d_ws;
  u16* Qh = base;                // [SEQ][DM] row-major
  u16* Ql = Qh + PL;             // FT
  u16* Kh = Ql + PL;             // row-major
  u16* Kl = Kh + PL;             // FT
  u16* Vt = Kl + PL;             // [DM][SEQ]
  u16* P  = base;                // [SEQ][SEQ] bf16, overlays Qh+Ql (dead by then)
  u16* regA = Vt + PL;           // offset 80 MiB
  u16* Xh  = regA;               // [SEQ][DM] row-major
  u16* Xl  = Xh + PL;            // FT
  u16* Wqh = Xl + PL;            // [DM][DM] transposed row-major
  u16* Wql = Wqh + WL;           // FT
  u16* Wkh = Wql + WL;
  u16* Wkl = Wkh + WL;
  u16* Wvh = Wkl + WL;
  float* S = (float*)regA;       // [SEQ][SEQ] fp32 overlays Xh..Wkl (dead when
                                 // k_scores runs; Wvh sits just past S's end)

  const float rscale = 1.0f / sqrtf(2048.0f);
  dim3 blk(256);
  k_split_all<<<dim3(4096 + 3 * 1024), blk, 0, stream>>>(x, Xh, Xl, Wq, Wk, Wv,
                                                         Wqh, Wql, Wkh, Wkl, Wvh);
  k_proj_qkv<<<dim3(DM / 128, SEQ / 128, 3), blk, 0, stream>>>(
      Xh, Xl, Wqh, Wql, Wkh, Wkl, Wvh, Qh, Ql, Kh, Kl, Vt, rscale);
  k_scores<<<dim3(NSC), blk, 0, stream>>>(Qh, Ql, Kh, Kl, S);
  k_softmax_dropout<<<dim3(SEQ), blk, 0, stream>>>(S, P);
  k_pv<<<dim3(DM / 128, SEQ / 128), blk, 0, stream>>>(P, Vt, (float*)d_out);
}

// Round 7
// 656.942 us; speedup vs baseline: 1.0374x; 1.0126x over previous
//
#include <hip/hip_runtime.h>
#include <cstdint>
#include <cstddef>
#include <cmath>

#define SEQ 4096
#define DM  2048
#define NSC ((SEQ / 128) * (SEQ / 128 + 1) / 2)   // 528 scores tiles

typedef unsigned int u32;
typedef unsigned short u16;
typedef __attribute__((ext_vector_type(8))) short bf16x8;
typedef __attribute__((ext_vector_type(4))) float f32x4;
typedef __attribute__((ext_vector_type(16))) float f32x16;

// ---------------- bf16 helpers (RNE) ----------------
__device__ __forceinline__ u16 f2bf(float f) {
  u32 u = __float_as_uint(f);
  return (u16)((u + 0x7FFFu + ((u >> 16) & 1u)) >> 16);
}
__device__ __forceinline__ float bf2f(u16 h) { return __uint_as_float(((u32)h) << 16); }

// ---------------- threefry dropout (verified round 1, variant 0) ----------------
__device__ __forceinline__ u32 rotl32(u32 x, int r) { return (x << r) | (x >> (32 - r)); }

__device__ __forceinline__ void tf2x32(u32 c0, u32 c1, u32& o0, u32& o1) {
  const u32 k0 = 0u, k1 = 42u, k2 = 0x1BD11BDAu ^ 0u ^ 42u;
  u32 x0 = c0 + k0;
  u32 x1 = c1 + k1;
#define TFR(r) { x0 += x1; x1 = rotl32(x1, (r)); x1 ^= x0; }
  TFR(13) TFR(15) TFR(26) TFR(6)   x0 += k1; x1 += k2 + 1u;
  TFR(17) TFR(29) TFR(16) TFR(24)  x0 += k2; x1 += k0 + 2u;
  TFR(13) TFR(15) TFR(26) TFR(6)   x0 += k0; x1 += k1 + 3u;
  TFR(17) TFR(29) TFR(16) TFR(24)  x0 += k1; x1 += k2 + 4u;
  TFR(13) TFR(15) TFR(26) TFR(6)   x0 += k2; x1 += k0 + 5u;
#undef TFR
  o0 = x0; o1 = x1;
}

__device__ __forceinline__ bool dropout_keep(u32 idx) {
  u32 a, b; tf2x32(0u, idx, a, b);
  return (((a ^ b) & 0x80000000u) == 0u);
}

// ---------------- async global -> LDS, 16 B/lane ----------------
__device__ __forceinline__ void g2l16(const void* g, void* l) {
  __builtin_amdgcn_global_load_lds((const __attribute__((address_space(1))) u32*)g,
                                   (__attribute__((address_space(3))) u32*)l, 16, 0, 0);
}

#define MFMA16(a, b, c) __builtin_amdgcn_mfma_f32_16x16x32_bf16(a, b, c, 0, 0, 0)
#define MFMA32(a, b, c) __builtin_amdgcn_mfma_f32_32x32x16_bf16(a, b, c, 0, 0, 0)

// FT32 layout (for 32x32x16 A/B operands) of [R rows][K k]:
// tile = 32 rows x 16 k; elem (rt, kt, lane, j) at (((rt*(K/16)+kt)*64+lane)*8+j)
// where lane holds row rt*32+(lane&31), k = kt*16+(lane>>5)*8+j.

// ---------------------------------------------------------------------------
// SPLIT MFMA GEMM core, 32x32x16, BK=64: C[128x128] = A*B^T (fp32 via hi/lo).
// hi: row-major via swizzled global_load_lds; lo: FT32 direct global->VGPR.
// smem: 16384 u16 (32 KB). acc: 2x2 tiles of 32x32 per wave (64x64 quadrant).
// ---------------------------------------------------------------------------
__device__ __forceinline__ void gemm_core_split(
    const u16* __restrict__ Ah, const u16* __restrict__ AlFT,
    const u16* __restrict__ Bh, const u16* __restrict__ BlFT,
    int lda, int ldb, int rowBlock, int colBlock, int kmax,
    f32x16 (&acc)[2][2], u16* smem)
{
  u16* Als = smem;
  u16* Bls = smem + 8192;
  const int tid  = threadIdx.x;
  const int wid  = tid >> 6;
  const int lane = tid & 63;
  const int wr   = (wid & 1) << 6;
  const int wc   = (wid >> 1) << 6;
  const int l31  = lane & 31;
  const int lh   = lane >> 5;                 // k-half within a 16-k chunk
  const int srow = wid * 32 + (lane >> 2);
  const int skol = (((lane & 3) ^ ((lane >> 3) & 3)) << 3);
  const int KA16 = lda >> 4, KB16 = ldb >> 4;
  const int rtA0 = (rowBlock >> 5) + ((wid & 1) << 1);
  const int rtB0 = (colBlock >> 5) + ((wid >> 1) << 1);
  const int swz  = (l31 >> 1) & 3;            // hi-LDS chunk swizzle (row-derived)

  const f32x16 zero = {0.f,0.f,0.f,0.f,0.f,0.f,0.f,0.f,0.f,0.f,0.f,0.f,0.f,0.f,0.f,0.f};
#pragma unroll
  for (int i = 0; i < 2; ++i)
#pragma unroll
    for (int j = 0; j < 2; ++j) acc[i][j] = zero;

  for (int kb = 0; kb < kmax; kb += 64) {
#pragma unroll
    for (int h = 0; h < 2; ++h)
#pragma unroll
      for (int t = 0; t < 2; ++t) {
        const size_t ga = (size_t)(rowBlock + srow + t * 16) * lda + kb + h * 32 + skol;
        const size_t gb = (size_t)(colBlock + srow + t * 16) * ldb + kb + h * 32 + skol;
        const int lo = h * 4096 + (wid * 32 + t * 16) * 32;
        g2l16(Ah + ga, &Als[lo]);
        g2l16(Bh + gb, &Bls[lo]);
      }
    __syncthreads();

#pragma unroll
    for (int q = 0; q < 4; ++q) {             // four 16-k chunks in BK=64
      const int h = q >> 1, s = q & 1;
      const int kt16 = (kb >> 4) + q;
      const int cl = s * 2 + lh;              // logical 16B chunk within 32-k half
      bf16x8 ah[2], bh[2], al[2], bl[2];
#pragma unroll
      for (int r = 0; r < 2; ++r) {
        const int rowA = wr + r * 32 + l31;
        const int rowB = wc + r * 32 + l31;
        ah[r] = *(const bf16x8*)&Als[h * 4096 + rowA * 32 + ((cl ^ swz) << 3)];
        bh[r] = *(const bf16x8*)&Bls[h * 4096 + rowB * 32 + ((cl ^ swz) << 3)];
        al[r] = *(const bf16x8*)(AlFT + (((size_t)(rtA0 + r) * KA16 + kt16) * 64 + lane) * 8);
        bl[r] = *(const bf16x8*)(BlFT + (((size_t)(rtB0 + r) * KB16 + kt16) * 64 + lane) * 8);
      }
#pragma unroll
      for (int r = 0; r < 2; ++r)
#pragma unroll
        for (int c = 0; c < 2; ++c) {
          acc[r][c] = MFMA32(ah[r], bh[c], acc[r][c]);
          acc[r][c] = MFMA32(ah[r], bl[c], acc[r][c]);
          acc[r][c] = MFMA32(al[r], bh[c], acc[r][c]);
        }
    }
    __syncthreads();
  }
}

// Plain bf16 GEMM core, 16x16x32, BK=64 (unchanged, proven): C = A * B^T.
__device__ __forceinline__ void gemm_core(
    const u16* __restrict__ Ah, const u16* __restrict__ Bh,
    int lda, int ldb, int rowBlock, int colBlock, int kmax,
    f32x4 (&acc)[4][4], u16* smem)
{
  u16* Als = smem;
  u16* Bls = smem + 8192;
  const int tid  = threadIdx.x;
  const int wid  = tid >> 6;
  const int lane = tid & 63;
  const int wr   = (wid & 1) << 6;
  const int wc   = (wid >> 1) << 6;
  const int lrow = lane & 15;
  const int lk   = (((lane >> 4) ^ ((lrow >> 1) & 3)) << 3);
  const int srow = wid * 32 + (lane >> 2);
  const int skol = (((lane & 3) ^ ((lane >> 3) & 3)) << 3);

  const f32x4 zero = {0.f, 0.f, 0.f, 0.f};
#pragma unroll
  for (int i = 0; i < 4; ++i)
#pragma unroll
    for (int j = 0; j < 4; ++j) acc[i][j] = zero;

  for (int kb = 0; kb < kmax; kb += 64) {
#pragma unroll
    for (int h = 0; h < 2; ++h)
#pragma unroll
      for (int t = 0; t < 2; ++t) {
        const size_t ga = (size_t)(rowBlock + srow + t * 16) * lda + kb + h * 32 + skol;
        const size_t gb = (size_t)(colBlock + srow + t * 16) * ldb + kb + h * 32 + skol;
        const int lo = h * 4096 + (wid * 32 + t * 16) * 32;
        g2l16(Ah + ga, &Als[lo]);
        g2l16(Bh + gb, &Bls[lo]);
      }
    __syncthreads();

#pragma unroll
    for (int h = 0; h < 2; ++h) {
      bf16x8 ah[4], bh[4];
#pragma unroll
      for (int r = 0; r < 4; ++r) {
        ah[r] = *(const bf16x8*)&Als[h * 4096 + (wr + r * 16 + lrow) * 32 + lk];
        bh[r] = *(const bf16x8*)&Bls[h * 4096 + (wc + r * 16 + lrow) * 32 + lk];
      }
#pragma unroll
      for (int r = 0; r < 4; ++r)
#pragma unroll
        for (int c = 0; c < 4; ++c)
          acc[r][c] = MFMA16(ah[r], bh[c], acc[r][c]);
    }
    __syncthreads();
  }
}

// ---------------- fused split/transpose preprocessing ----------------
__global__ __launch_bounds__(256) void k_split_all(
    const float* __restrict__ X, u16* __restrict__ Xh, u16* __restrict__ Xl,
    const float* __restrict__ Wq, const float* __restrict__ Wk, const float* __restrict__ Wv,
    u16* __restrict__ Wqh, u16* __restrict__ Wql,
    u16* __restrict__ Wkh, u16* __restrict__ Wkl, u16* __restrict__ Wvh) {
  __shared__ float t[64][65];
  const int bid = blockIdx.x;
  const int tid = threadIdx.x;
  const int wid = tid >> 6, lane = tid & 63;

  if (bid < 4096) {
    // X -> hi row-major + lo FT32 (tile = 32 rows x 16 k)
    const int kt16 = bid & 127;
    const int rt32 = (bid >> 7) * 4 + wid;
    const int row = rt32 * 32 + (lane & 31);
    const int col = kt16 * 16 + ((lane >> 5) << 3);
    const float* src = X + (size_t)row * DM + col;
    const float4 v0 = *(const float4*)src;
    const float4 v1 = *(const float4*)(src + 4);
    float v[8] = {v0.x, v0.y, v0.z, v0.w, v1.x, v1.y, v1.z, v1.w};
    u16 h[8], l[8];
#pragma unroll
    for (int j = 0; j < 8; ++j) {
      h[j] = f2bf(v[j]);
      l[j] = f2bf(v[j] - bf2f(h[j]));
    }
    u16* hp = Xh + (size_t)row * DM + col;
    *(ushort4*)hp = *(ushort4*)&h[0];
    *(ushort4*)(hp + 4) = *(ushort4*)&h[4];
    u16* lp = Xl + (((size_t)rt32 * 128 + kt16) * 64 + lane) * 8;
    *(ushort4*)lp = *(ushort4*)&l[0];
    *(ushort4*)(lp + 4) = *(ushort4*)&l[4];
    return;
  }

  const int r = bid - 4096;
  const int z = r >> 10;
  const int rem = r & 1023;
  const int n0 = (rem & 31) * 64, k0 = (rem >> 5) * 64;
  const float* W = (z == 0) ? Wq : (z == 1) ? Wk : Wv;
  u16* Oh = (z == 0) ? Wqh : (z == 1) ? Wkh : Wvh;
  u16* Ol = (z == 0) ? Wql : Wkl;
  const int tx = tid & 63, ty = tid >> 6;
#pragma unroll
  for (int i = 0; i < 16; ++i)
    t[ty * 16 + i][tx] = W[(size_t)(k0 + ty * 16 + i) * DM + n0 + tx];
  __syncthreads();
  {
    const int nl = tid >> 2, kc = (tid & 3) * 16;
    u16 h[16];
#pragma unroll
    for (int i = 0; i < 16; ++i) h[i] = f2bf(t[kc + i][nl]);
    u16* hp = Oh + (size_t)(n0 + nl) * DM + k0 + kc;
#pragma unroll
    for (int i = 0; i < 4; ++i) *(ushort4*)(hp + i * 4) = *(ushort4*)&h[i * 4];
  }
  if (z < 2) {
    // lo FT32 over transposed [n][k]: 64x64 block = 2 rt x 4 kt tiles, 2/wave
#pragma unroll
    for (int tt = 0; tt < 2; ++tt) {
      const int idx = wid * 2 + tt;       // 0..7
      const int rt = idx >> 2, kt = idx & 3;
      const int nl = rt * 32 + (lane & 31);
      const int kc = kt * 16 + ((lane >> 5) << 3);
      u16 l[8];
#pragma unroll
      for (int j = 0; j < 8; ++j) {
        const float v = t[kc + j][nl];
        l[j] = f2bf(v - bf2f(f2bf(v)));
      }
      const int rtg = (n0 >> 5) + rt, ktg = (k0 >> 4) + kt;
      u16* lp = Ol + (((size_t)rtg * (DM / 16) + ktg) * 64 + lane) * 8;
      *(ushort4*)lp = *(ushort4*)&l[0];
      *(ushort4*)(lp + 4) = *(ushort4*)&l[4];
    }
  }
}

// ---------------- fused Q/K/V projections ----------------
// z=0: Q (split32, *1/sqrt(d))  z=1: K (split32)  z=2: V (plain bf16 -> Vt).
__global__ __launch_bounds__(256) void k_proj_qkv(
    const u16* __restrict__ Xh, const u16* __restrict__ Xl,
    const u16* __restrict__ Wqh, const u16* __restrict__ Wql,
    const u16* __restrict__ Wkh, const u16* __restrict__ Wkl,
    const u16* __restrict__ Wvh,
    u16* __restrict__ Qh, u16* __restrict__ Ql,
    u16* __restrict__ Kh, u16* __restrict__ Kl,
    u16* __restrict__ Vt, float rscaleQ)
{
  __shared__ __align__(16) u16 smem[16384];
  const int z = blockIdx.z;
  const int rowBlock = blockIdx.y * 128, colBlock = blockIdx.x * 128;
  const int lane = threadIdx.x & 63, wid = threadIdx.x >> 6;

  if (z == 2) {
    f32x4 acc[4][4];
    gemm_core(Xh, Wvh, DM, DM, rowBlock, colBlock, DM, acc, smem);
    const int r0 = rowBlock + ((wid & 1) << 6) + ((lane >> 4) << 2);
    const int c0 = colBlock + ((wid >> 1) << 6) + (lane & 15);
#pragma unroll
    for (int r = 0; r < 4; ++r)
#pragma unroll
      for (int c = 0; c < 4; ++c) {
        ushort4 pk;
        pk.x = f2bf(acc[r][c][0]); pk.y = f2bf(acc[r][c][1]);
        pk.z = f2bf(acc[r][c][2]); pk.w = f2bf(acc[r][c][3]);
        *(ushort4*)(Vt + (size_t)(c0 + c * 16) * SEQ + r0 + r * 16) = pk;
      }
    return;
  }

  const u16* Bh = z ? Wkh : Wqh;
  const u16* Bl = z ? Wkl : Wql;
  u16* Oh = z ? Kh : Qh;
  u16* Ol = z ? Kl : Ql;
  const float rs = z ? 1.0f : rscaleQ;
  f32x16 acc[2][2];
  gemm_core_split(Xh, Xl, Bh, Bl, DM, DM, rowBlock, colBlock, DM, acc, smem);

  const int wr = (wid & 1) << 6, wc = (wid >> 1) << 6;
  const int l31 = lane & 31, lh = lane >> 5;
  // hi -> global row-major; lo -> chunk-swizzled smem (kills bank conflicts)
#pragma unroll
  for (int r = 0; r < 2; ++r)
#pragma unroll
    for (int c = 0; c < 2; ++c) {
      const int colL = wc + c * 32 + l31;
      const int colG = colBlock + colL;
#pragma unroll
      for (int g = 0; g < 4; ++g)
#pragma unroll
        for (int e = 0; e < 4; ++e) {
          const int rowL = wr + r * 32 + 4 * lh + e + 8 * g;
          const float v = acc[r][c][g * 4 + e] * rs;
          const u16 h = f2bf(v);
          Oh[(size_t)(rowBlock + rowL) * DM + colG] = h;
          smem[rowL * 128 + (((colL >> 3) ^ (rowL & 7)) << 3) + (colL & 7)] =
              f2bf(v - bf2f(h));
        }
    }
  __syncthreads();
  // lo: FT32 store (32 tiles of 32x16 per 128x128 block, 8/wave)
#pragma unroll
  for (int t8 = 0; t8 < 8; ++t8) {
    const int idx = wid * 8 + t8;        // 0..31
    const int rt = idx >> 3, kt = idx & 7;
    const int rowL = rt * 32 + l31;
    const int ch = kt * 2 + lh;          // logical 16B chunk (8 u16)
    const bf16x8 vL = *(const bf16x8*)&smem[rowL * 128 + ((ch ^ (rowL & 7)) << 3)];
    const int rtg = (rowBlock >> 5) + rt, ktg = (colBlock >> 4) + kt;
    *(bf16x8*)(Ol + (((size_t)rtg * (DM / 16) + ktg) * 64 + lane) * 8) = vL;
  }
}

// S = (Q/scale) @ K^T (split32), 528 lower-triangular blocks, fp32 out.
__global__ __launch_bounds__(256) void k_scores(
    const u16* __restrict__ Qh, const u16* __restrict__ Ql,
    const u16* __restrict__ Kh, const u16* __restrict__ Kl, float* __restrict__ S)
{
  __shared__ __align__(16) u16 smem[16384];
  const int bid = blockIdx.x;
  int by = (int)((sqrtf(8.0f * (float)bid + 1.0f) - 1.0f) * 0.5f);
  while ((by + 1) * (by + 2) / 2 <= bid) ++by;
  while (by * (by + 1) / 2 > bid) --by;
  const int bx = bid - by * (by + 1) / 2;

  f32x16 acc[2][2];
  gemm_core_split(Qh, Ql, Kh, Kl, DM, DM, by * 128, bx * 128, DM, acc, smem);

  const int lane = threadIdx.x & 63, wid = threadIdx.x >> 6;
  const int wr = (wid & 1) << 6, wc = (wid >> 1) << 6;
  const int l31 = lane & 31, lh = lane >> 5;
  const int r0 = by * 128 + wr, c0 = bx * 128 + wc;
#pragma unroll
  for (int r = 0; r < 2; ++r)
#pragma unroll
    for (int c = 0; c < 2; ++c) {
      const int col = c0 + c * 32 + l31;
#pragma unroll
      for (int g = 0; g < 4; ++g)
#pragma unroll
        for (int e = 0; e < 4; ++e) {
          const int row = r0 + r * 32 + 4 * lh + e + 8 * g;
          S[(size_t)row * SEQ + col] = acc[r][c][g * 4 + e];
        }
    }
}

// Row softmax (causal) + inverted dropout; S fp32 -> P bf16 (zero-padded to 128).
__global__ __launch_bounds__(256) void k_softmax_dropout(const float* __restrict__ S,
                                                         u16* __restrict__ P) {
  const int row = blockIdx.x;
  const int n = row + 1;
  const int nt = (n + 1023) >> 10;
  const int tid = threadIdx.x;
  __shared__ float buf[SEQ];
  __shared__ float red[4];
  __shared__ float bcast;
  const float* srow = S + (size_t)row * SEQ;

  float lmax = -INFINITY;
  for (int t = 0; t < nt; ++t) {
    int j4 = tid + t * 256;
    float4 v = *(const float4*)(srow + (size_t)j4 * 4);
    int b = j4 * 4;
    float x0 = (b + 0 < n) ? v.x : -INFINITY;
    float x1 = (b + 1 < n) ? v.y : -INFINITY;
    float x2 = (b + 2 < n) ? v.z : -INFINITY;
    float x3 = (b + 3 < n) ? v.w : -INFINITY;
    buf[b + 0] = x0; buf[b + 1] = x1; buf[b + 2] = x2; buf[b + 3] = x3;
    lmax = fmaxf(lmax, fmaxf(fmaxf(x0, x1), fmaxf(x2, x3)));
  }
  for (int off = 32; off > 0; off >>= 1) lmax = fmaxf(lmax, __shfl_down(lmax, off, 64));
  if ((tid & 63) == 0) red[tid >> 6] = lmax;
  __syncthreads();
  if (tid == 0) bcast = fmaxf(fmaxf(red[0], red[1]), fmaxf(red[2], red[3]));
  __syncthreads();
  const float m = bcast;

  float lsum = 0.f;
  for (int t = 0; t < nt; ++t) {
    int b = (tid + t * 256) * 4;
    float e0 = expf(buf[b + 0] - m);
    float e1 = expf(buf[b + 1] - m);
    float e2 = expf(buf[b + 2] - m);
    float e3 = expf(buf[b + 3] - m);
    buf[b + 0] = e0; buf[b + 1] = e1; buf[b + 2] = e2; buf[b + 3] = e3;
    lsum += (e0 + e1) + (e2 + e3);
  }
  for (int off = 32; off > 0; off >>= 1) lsum += __shfl_down(lsum, off, 64);
  if ((tid & 63) == 0) red[tid >> 6] = lsum;
  __syncthreads();
  if (tid == 0) bcast = (red[0] + red[1]) + (red[2] + red[3]);
  __syncthreads();
  const float total = bcast;

  u16* prow = P + (size_t)row * SEQ;
  const int zeroEnd = ((row >> 7) + 1) << 7;
  for (int j = tid; j < zeroEnd; j += 256) {
    float out = 0.f;
    if (j < n) {
      const float w = buf[j] / total;
      out = dropout_keep((u32)(row * SEQ + j)) ? w * 2.0f : 0.f;
    }
    prow[j] = f2bf(out);
  }
}

// context = P @ V (plain bf16, causal-truncated K-loop), fp32 out; heavy rows first.
__global__ __launch_bounds__(256) void k_pv(const u16* __restrict__ P,
                                            const u16* __restrict__ Vt,
                                            float* __restrict__ O) {
  __shared__ __align__(16) u16 smem[16384];
  const int by = (SEQ / 128 - 1) - blockIdx.y;
  f32x4 acc[4][4];
  gemm_core(P, Vt, SEQ, SEQ, by * 128, blockIdx.x * 128, (by + 1) * 128, acc, smem);

  const int lane = threadIdx.x & 63, wid = threadIdx.x >> 6;
  const int r0 = by * 128 + ((wid & 1) << 6) + ((lane >> 4) << 2);
  const int c0 = blockIdx.x * 128 + ((wid >> 1) << 6) + (lane & 15);
#pragma unroll
  for (int r = 0; r < 4; ++r)
#pragma unroll
    for (int c = 0; c < 4; ++c)
#pragma unroll
      for (int e = 0; e < 4; ++e)
        O[(size_t)(r0 + r * 16 + e) * DM + (c0 + c * 16)] = acc[r][c][e];
}

extern "C" void kernel_launch(void* const* d_in, const int* in_sizes, int n_in,
                              void* d_out, int out_size, void* d_ws, size_t ws_size,
                              hipStream_t stream) {
  const float* x  = (const float*)d_in[0];
  const float* Wq = (const float*)d_in[1];
  const float* Wk = (const float*)d_in[2];
  const float* Wv = (const float*)d_in[3];

  // workspace layout (u16 elements; <=152 MiB). FT32 planes same sizes as before.
  const size_t PL = (size_t)SEQ * DM;   // 16 MiB/plane
  const size_t WL = (size_t)DM * DM;    // 8 MiB/plane
  u16* base = (u16*)d_ws;
  u16* Qh = base;                // [SEQ][DM] row-major
  u16* Ql = Qh + PL;             // FT32
  u16* Kh = Ql + PL;             // row-major
  u16* Kl = Kh + PL;             // FT32
  u16* Vt = Kl + PL;             // [DM][SEQ]
  u16* P  = base;                // [SEQ][SEQ] bf16, overlays Qh+Ql (dead by then)
  u16* regA = Vt + PL;           // offset 80 MiB
  u16* Xh  = regA;               // [SEQ][DM] row-major
  u16* Xl  = Xh + PL;            // FT32
  u16* Wqh = Xl + PL;            // [DM][DM] transposed row-major
  u16* Wql = Wqh + WL;           // FT32
  u16* Wkh = Wql + WL;
  u16* Wkl = Wkh + WL;
  u16* Wvh = Wkl + WL;
  float* S = (float*)regA;       // [SEQ][SEQ] fp32 overlays Xh..Wkl (dead when
                                 // k_scores runs; Wvh sits just past S's end)

  const float rscale = 1.0f / sqrtf(2048.0f);
  dim3 blk(256);
  k_split_all<<<dim3(4096 + 3 * 1024), blk, 0, stream>>>(x, Xh, Xl, Wq, Wk, Wv,
                                                         Wqh, Wql, Wkh, Wkl, Wvh);
  k_proj_qkv<<<dim3(DM / 128, SEQ / 128, 3), blk, 0, stream>>>(
      Xh, Xl, Wqh, Wql, Wkh, Wkl, Wvh, Qh, Ql, Kh, Kl, Vt, rscale);
  k_scores<<<dim3(NSC), blk, 0, stream>>>(Qh, Ql, Kh, Kl, S);
  k_softmax_dropout<<<dim3(SEQ), blk, 0, stream>>>(S, P);
  k_pv<<<dim3(DM / 128, SEQ / 128), blk, 0, stream>>>(P, Vt, (float*)d_out);
}